// Round 3
// baseline (542.918 us; speedup 1.0000x reference)
//
#include <hip/hip_runtime.h>
#include <hip/hip_bf16.h>
#include <cstdint>
#include <cstddef>

#define DEVI __device__ __forceinline__

typedef __attribute__((ext_vector_type(8))) short bf16x8;
typedef __attribute__((ext_vector_type(4))) float f32x4;

DEVI unsigned short f2bf(float f){
  unsigned u; __builtin_memcpy(&u, &f, 4);
  u += 0x7fffu + ((u >> 16) & 1u);
  return (unsigned short)(u >> 16);
}

DEVI f32x4 mfma_bf16(bf16x8 a, bf16x8 b, f32x4 c){
  return __builtin_amdgcn_mfma_f32_16x16x32_bf16(a, b, c, 0, 0, 0);
}

DEVI float exp2fast(float x){ return __builtin_amdgcn_exp2f(x); }

#define GLDS16(gp, lp) __builtin_amdgcn_global_load_lds( \
    (const __attribute__((address_space(1))) void*)(gp), \
    (__attribute__((address_space(3))) void*)(lp), 16, 0, 0)

// ---------------------------------------------------------------------------
// W fp32 [K=1024][N=1024] -> Wt bf16 [N][K]
__global__ __launch_bounds__(256) void transpose_w(const float* __restrict__ W,
                                                   unsigned short* __restrict__ Wt){
  __shared__ float tile[32][33];
  int bx = blockIdx.x * 32;  // n block
  int by = blockIdx.y * 32;  // k block
  int tx = threadIdx.x, ty = threadIdx.y;
  #pragma unroll
  for (int j = 0; j < 32; j += 8)
    tile[ty + j][tx] = W[(size_t)(by + ty + j) * 1024 + bx + tx];
  __syncthreads();
  #pragma unroll
  for (int j = 0; j < 32; j += 8)
    Wt[(size_t)(bx + ty + j) * 1024 + by + tx] = f2bf(tile[tx][ty + j]);
}

__global__ __launch_bounds__(256) void concat_bias(const float* __restrict__ a,
                                                   const float* __restrict__ b,
                                                   const float* __restrict__ c,
                                                   float* __restrict__ o){
  int i = blockIdx.x * 256 + threadIdx.x;
  o[i] = (i < 1024) ? a[i] : ((i < 2048) ? b[i - 1024] : c[i - 2048]);
}

// ---------------------------------------------------------------------------
// LayerNorm: fp32 row[1024] -> bf16 row
__global__ __launch_bounds__(256) void ln_kernel(const float* __restrict__ x,
                                                 const float* __restrict__ g,
                                                 const float* __restrict__ b,
                                                 unsigned short* __restrict__ out){
  int row = blockIdx.x, t = threadIdx.x, lane = t & 63, wid = t >> 6;
  const float4* xr = (const float4*)(x + (size_t)row * 1024);
  float4 v = xr[t];
  float s = v.x + v.y + v.z + v.w;
  #pragma unroll
  for (int o = 32; o >= 1; o >>= 1) s += __shfl_xor(s, o, 64);
  __shared__ float red[8];
  if (lane == 0) red[wid] = s;
  __syncthreads();
  float mu = (red[0] + red[1] + red[2] + red[3]) * (1.0f / 1024.0f);
  float d0 = v.x - mu, d1 = v.y - mu, d2 = v.z - mu, d3 = v.w - mu;
  float ss = d0*d0 + d1*d1 + d2*d2 + d3*d3;
  #pragma unroll
  for (int o = 32; o >= 1; o >>= 1) ss += __shfl_xor(ss, o, 64);
  if (lane == 0) red[4 + wid] = ss;
  __syncthreads();
  float var = (red[4] + red[5] + red[6] + red[7]) * (1.0f / 1024.0f);
  float rs = rsqrtf(var + 1e-5f);
  float4 gv = ((const float4*)g)[t];
  float4 bv = ((const float4*)b)[t];
  ushort4 o4;
  o4.x = f2bf(d0 * rs * gv.x + bv.x);
  o4.y = f2bf(d1 * rs * gv.y + bv.y);
  o4.z = f2bf(d2 * rs * gv.z + bv.z);
  o4.w = f2bf(d3 * rs * gv.w + bv.w);
  *(ushort4*)(out + (size_t)row * 1024 + t * 4) = o4;
}

// ---------------------------------------------------------------------------
// GEMM: A bf16 [M][1024] x Wt bf16 [N][1024]^T (+bias). EPI: 0=bf16 out,
// 1=gelu->bf16 out, 2=+res(fp32)->fp32 out.  m97 structure: 128x128, BK=32.
template<int EPI>
__global__ __launch_bounds__(256) void gemm_bt(const unsigned short* __restrict__ A,
                                               const unsigned short* __restrict__ Bt,
                                               const float* __restrict__ bias,
                                               const float* __restrict__ res,
                                               void* __restrict__ outp){
  const int K = 1024, N = 1024;
  __shared__ short As[128 * 32];
  __shared__ short Bs[128 * 32];
  int t = threadIdx.x, lane = t & 63, w = t >> 6;
  int wm = w >> 1, wn = w & 1;
  int m0 = blockIdx.y * 128, n0 = blockIdx.x * 128;
  f32x4 acc[4][4] = {};
  for (int k0 = 0; k0 < K; k0 += 32){
    __syncthreads();
    #pragma unroll
    for (int j = 0; j < 2; j++){
      int c = t + j * 256;
      int r = c >> 2, col = (c & 3) * 8;
      unsigned ldsb = (unsigned)(w * 1024 + j * 4096);
      GLDS16(A  + (size_t)(m0 + r) * K + k0 + col, (char*)As + ldsb);
      GLDS16(Bt + (size_t)(n0 + r) * K + k0 + col, (char*)Bs + ldsb);
    }
    __syncthreads();
    bf16x8 af[4], bf[4];
    #pragma unroll
    for (int mi = 0; mi < 4; mi++)
      af[mi] = *(const bf16x8*)(As + (wm*64 + mi*16 + (lane & 15)) * 32 + (lane >> 4) * 8);
    #pragma unroll
    for (int ni = 0; ni < 4; ni++)
      bf[ni] = *(const bf16x8*)(Bs + (wn*64 + ni*16 + (lane & 15)) * 32 + (lane >> 4) * 8);
    #pragma unroll
    for (int mi = 0; mi < 4; mi++)
      #pragma unroll
      for (int ni = 0; ni < 4; ni++)
        acc[mi][ni] = mfma_bf16(af[mi], bf[ni], acc[mi][ni]);
  }
  #pragma unroll
  for (int mi = 0; mi < 4; mi++){
    #pragma unroll
    for (int ni = 0; ni < 4; ni++){
      #pragma unroll
      for (int r = 0; r < 4; r++){
        int row = m0 + wm*64 + mi*16 + ((lane >> 4) << 2) + r;
        int col = n0 + wn*64 + ni*16 + (lane & 15);
        float v = acc[mi][ni][r] + bias[col];
        if (EPI == 1) v = 0.5f * v * (1.0f + erff(v * 0.70710678118654752f));
        if (EPI == 2){
          v += res[(size_t)row * N + col];
          ((float*)outp)[(size_t)row * N + col] = v;
        } else {
          ((unsigned short*)outp)[(size_t)row * N + col] = f2bf(v);
        }
      }
    }
  }
}

// ---------------------------------------------------------------------------
// Fused QKV GEMM: A bf16 [4096][1024] x WQKV bf16 [3072][1024]^T + bias.
// Writes q,k head-major [b][h][s][64] and v transposed [b][h][64][s].
__global__ __launch_bounds__(256) void gemm_qkv(const unsigned short* __restrict__ A,
                                                const unsigned short* __restrict__ Bt,
                                                const float* __restrict__ bias,
                                                unsigned short* __restrict__ qh,
                                                unsigned short* __restrict__ kh,
                                                unsigned short* __restrict__ vt){
  const int K = 1024;
  __shared__ short As[128 * 32];
  __shared__ short Bs[128 * 32];
  int t = threadIdx.x, lane = t & 63, w = t >> 6;
  int wm = w >> 1, wn = w & 1;
  int m0 = blockIdx.y * 128, n0 = blockIdx.x * 128;
  f32x4 acc[4][4] = {};
  for (int k0 = 0; k0 < K; k0 += 32){
    __syncthreads();
    #pragma unroll
    for (int j = 0; j < 2; j++){
      int c = t + j * 256;
      int r = c >> 2, col = (c & 3) * 8;
      unsigned ldsb = (unsigned)(w * 1024 + j * 4096);
      GLDS16(A  + (size_t)(m0 + r) * K + k0 + col, (char*)As + ldsb);
      GLDS16(Bt + (size_t)(n0 + r) * K + k0 + col, (char*)Bs + ldsb);
    }
    __syncthreads();
    bf16x8 af[4], bf[4];
    #pragma unroll
    for (int mi = 0; mi < 4; mi++)
      af[mi] = *(const bf16x8*)(As + (wm*64 + mi*16 + (lane & 15)) * 32 + (lane >> 4) * 8);
    #pragma unroll
    for (int ni = 0; ni < 4; ni++)
      bf[ni] = *(const bf16x8*)(Bs + (wn*64 + ni*16 + (lane & 15)) * 32 + (lane >> 4) * 8);
    #pragma unroll
    for (int mi = 0; mi < 4; mi++)
      #pragma unroll
      for (int ni = 0; ni < 4; ni++)
        acc[mi][ni] = mfma_bf16(af[mi], bf[ni], acc[mi][ni]);
  }
  int ln15 = lane & 15, g = lane >> 4;
  #pragma unroll
  for (int mi = 0; mi < 4; mi++){
    #pragma unroll
    for (int ni = 0; ni < 4; ni++){
      int cnb = n0 + wn*64 + ni*16;            // frag col base (wave-uniform)
      int sel = cnb >> 10;
      int hh = (cnb & 1023) >> 6;
      int d = (cnb & 63) + ln15;
      int row0 = m0 + wm*64 + mi*16 + g*4;
      int b = row0 >> 11, s0 = row0 & 2047;
      float v4[4];
      #pragma unroll
      for (int r = 0; r < 4; r++) v4[r] = acc[mi][ni][r] + bias[cnb + ln15];
      if (sel == 2){
        ushort4 u;
        u.x = f2bf(v4[0]); u.y = f2bf(v4[1]); u.z = f2bf(v4[2]); u.w = f2bf(v4[3]);
        *(ushort4*)(vt + ((size_t)(b*16 + hh)*64 + d)*2048 + s0) = u;
      } else {
        unsigned short* dst = (sel == 0) ? qh : kh;
        #pragma unroll
        for (int r = 0; r < 4; r++)
          dst[((size_t)(b*16 + hh)*2048 + s0 + r)*64 + d] = f2bf(v4[r]);
      }
    }
  }
}

// ---------------------------------------------------------------------------
// Flash attention, swapped operands, zero barriers, direct global frag loads.
// Grid (32, 32): x -> (h,b), y -> qt (reversed: heavy first). 4 waves/block,
// wave w owns q rows qt*64 + w*16 .. +15.
__global__ __launch_bounds__(256) void flash_kernel(const unsigned short* __restrict__ Qh,
                                                    const unsigned short* __restrict__ Kh,
                                                    const unsigned short* __restrict__ Vt,
                                                    unsigned short* __restrict__ CTX,
                                                    float* __restrict__ Mo,
                                                    float* __restrict__ Lo){
  const float SC = 0.18033688011112042f;   // log2(e)/8
  int qt = 31 - blockIdx.y;
  int h = blockIdx.x >> 1, b = blockIdx.x & 1;
  int bh = b * 16 + h;
  int t = threadIdx.x, lane = t & 63, w = t >> 6;
  int ln15 = lane & 15, g = lane >> 4;
  int q = qt * 64 + w * 16 + ln15;         // this lane's q row (B/C col index)
  __shared__ short Ps[4][16][80];          // wave-private P tile, stride 160B

  const unsigned short* qp = Qh + ((size_t)bh * 2048 + q) * 64 + g * 8;
  bf16x8 bq0 = *(const bf16x8*)(qp);
  bf16x8 bq1 = *(const bf16x8*)(qp + 32);
  f32x4 acc[4] = {};
  float m2 = -1e30f, l = 0.f;

  for (int kt = 0; kt <= qt; kt++){
    const unsigned short* kp = Kh + ((size_t)bh * 2048 + kt * 64 + ln15) * 64 + g * 8;
    // scores^T = K * Q : out[m=kcol][n=q]
    f32x4 sf[4];
    #pragma unroll
    for (int kf = 0; kf < 4; kf++){
      bf16x8 a0 = *(const bf16x8*)(kp + (size_t)kf * 16 * 64);
      bf16x8 a1 = *(const bf16x8*)(kp + (size_t)kf * 16 * 64 + 32);
      f32x4 z = {};
      z = mfma_bf16(a0, bq0, z);
      z = mfma_bf16(a1, bq1, z);
      sf[kf] = z;
    }
    float s2[16];
    bool diag = (kt == qt);
    #pragma unroll
    for (int kf = 0; kf < 4; kf++)
      #pragma unroll
      for (int r = 0; r < 4; r++){
        float v = sf[kf][r] * SC;
        if (diag && (kt * 64 + kf * 16 + g * 4 + r > q)) v = -1e30f;
        s2[kf * 4 + r] = v;
      }
    // row max: 15 register max + 2 shfl (row lives in lanes {l, l^16, l^32, l^48})
    float tm = s2[0];
    #pragma unroll
    for (int i = 1; i < 16; i++) tm = fmaxf(tm, s2[i]);
    tm = fmaxf(tm, __shfl_xor(tm, 16, 64));
    tm = fmaxf(tm, __shfl_xor(tm, 32, 64));
    if (!__all(tm <= m2 + 8.0f)){          // T13 defer-max
      float mn = fmaxf(m2, tm);
      float sc = exp2fast(m2 - mn);
      l *= sc;
      #pragma unroll
      for (int df = 0; df < 4; df++)
        #pragma unroll
        for (int r = 0; r < 4; r++) acc[df][r] *= sc;
      m2 = mn;
    }
    float p[16], ps = 0.f;
    #pragma unroll
    for (int i = 0; i < 16; i++){ p[i] = exp2fast(s2[i] - m2); ps += p[i]; }
    ps += __shfl_xor(ps, 16, 64);
    ps += __shfl_xor(ps, 32, 64);
    l += ps;
    // pack P -> wave-private LDS (row = q-local = ln15, col = kcol-local)
    #pragma unroll
    for (int kf = 0; kf < 4; kf++){
      ushort4 u;
      u.x = f2bf(p[kf*4+0]); u.y = f2bf(p[kf*4+1]);
      u.z = f2bf(p[kf*4+2]); u.w = f2bf(p[kf*4+3]);
      *(ushort4*)&Ps[w][ln15][kf * 16 + g * 4] = u;
    }
    bf16x8 bp0 = *(const bf16x8*)&Ps[w][ln15][g * 8];
    bf16x8 bp1 = *(const bf16x8*)&Ps[w][ln15][32 + g * 8];
    // ctx^T += V^T * P : out[m=d][n=q]
    const unsigned short* vp = Vt + ((size_t)bh * 64 + ln15) * 2048 + kt * 64 + g * 8;
    #pragma unroll
    for (int df = 0; df < 4; df++){
      bf16x8 a0 = *(const bf16x8*)(vp + (size_t)df * 16 * 2048);
      bf16x8 a1 = *(const bf16x8*)(vp + (size_t)df * 16 * 2048 + 32);
      acc[df] = mfma_bf16(a0, bp0, acc[df]);
      acc[df] = mfma_bf16(a1, bp1, acc[df]);
    }
  }
  float inv = 1.0f / l;
  #pragma unroll
  for (int df = 0; df < 4; df++){
    ushort4 u;
    u.x = f2bf(acc[df][0] * inv); u.y = f2bf(acc[df][1] * inv);
    u.z = f2bf(acc[df][2] * inv); u.w = f2bf(acc[df][3] * inv);
    *(ushort4*)(CTX + ((size_t)(b * 2048 + q)) * 1024 + h * 64 + df * 16 + g * 4) = u;
  }
  if (g == 0){
    Mo[(size_t)bh * 2048 + q] = m2;
    Lo[(size_t)bh * 2048 + q] = inv;       // store 1/l for amean
  }
}

// ---------------------------------------------------------------------------
// Head-averaged attention probabilities, no LDS, direct global frags.
__global__ __launch_bounds__(256) void amean_kernel(const unsigned short* __restrict__ Qh,
                                                    const unsigned short* __restrict__ Kh,
                                                    const float* __restrict__ Mo,
                                                    const float* __restrict__ Lo,
                                                    float* __restrict__ outA){
  const float SC = 0.18033688011112042f;
  int kt = blockIdx.x, qt = blockIdx.y, b = blockIdx.z;
  int q0 = qt * 64, k0 = kt * 64;
  int t = threadIdx.x;
  if (kt > qt){
    float4 z = {0.f, 0.f, 0.f, 0.f};
    #pragma unroll
    for (int i = 0; i < 4; i++){
      int c = t + i * 256; int r = c >> 4, col = (c & 15) * 4;
      *(float4*)(outA + (size_t)(b*2048 + q0 + r) * 2048 + k0 + col) = z;
    }
    return;
  }
  int lane = t & 63, w = t >> 6, ln15 = lane & 15, g = lane >> 4;
  int qA = q0 + w * 16 + ln15;
  int qc0 = q0 + w * 16 + g * 4;
  bool diag = (kt == qt);
  f32x4 am[4] = {};
  for (int h = 0; h < 16; h++){
    int bh = b * 16 + h;
    const unsigned short* qp = Qh + ((size_t)bh * 2048 + qA) * 64 + g * 8;
    bf16x8 a0 = *(const bf16x8*)qp;
    bf16x8 a1 = *(const bf16x8*)(qp + 32);
    float mh[4], li[4];
    #pragma unroll
    for (int r = 0; r < 4; r++){
      mh[r] = Mo[(size_t)bh * 2048 + qc0 + r];
      li[r] = Lo[(size_t)bh * 2048 + qc0 + r] * 0.0625f;   // (1/l)/16
    }
    #pragma unroll
    for (int kf = 0; kf < 4; kf++){
      const unsigned short* kp = Kh + ((size_t)bh * 2048 + k0 + kf * 16 + ln15) * 64 + g * 8;
      bf16x8 b0 = *(const bf16x8*)kp;
      bf16x8 b1 = *(const bf16x8*)(kp + 32);
      f32x4 z = {};
      z = mfma_bf16(a0, b0, z);
      z = mfma_bf16(a1, b1, z);
      #pragma unroll
      for (int r = 0; r < 4; r++){
        float a = exp2fast(z[r] * SC - mh[r]) * li[r];
        if (diag && (k0 + kf * 16 + ln15 > qc0 + r)) a = 0.f;
        am[kf][r] += a;
      }
    }
  }
  #pragma unroll
  for (int kf = 0; kf < 4; kf++)
    #pragma unroll
    for (int r = 0; r < 4; r++)
      outA[(size_t)(b*2048 + qc0 + r) * 2048 + k0 + kf * 16 + ln15] = am[kf][r];
}

// ---------------------------------------------------------------------------
extern "C" void kernel_launch(void* const* d_in, const int* in_sizes, int n_in,
                              void* d_out, int out_size, void* d_ws, size_t ws_size,
                              hipStream_t stream){
  const float* x   = (const float*)d_in[0];
  const float* Wq  = (const float*)d_in[1];
  const float* bq  = (const float*)d_in[2];
  const float* Wk  = (const float*)d_in[3];
  const float* bk  = (const float*)d_in[4];
  const float* Wv  = (const float*)d_in[5];
  const float* bv  = (const float*)d_in[6];
  const float* Wo  = (const float*)d_in[7];
  const float* bo  = (const float*)d_in[8];
  const float* g1  = (const float*)d_in[9];
  const float* b1  = (const float*)d_in[10];
  const float* g2  = (const float*)d_in[11];
  const float* b2  = (const float*)d_in[12];
  const float* Wm1 = (const float*)d_in[13];
  const float* bm1 = (const float*)d_in[14];
  const float* Wm2 = (const float*)d_in[15];
  const float* bm2 = (const float*)d_in[16];

  char* ws = (char*)d_ws;
  const size_t MB = (size_t)1 << 20;
  unsigned short* wqkv = (unsigned short*)(ws + 0*MB);    // 6 MB
  unsigned short* wto  = (unsigned short*)(ws + 6*MB);    // 2 MB
  unsigned short* wtm1 = (unsigned short*)(ws + 8*MB);    // 2 MB
  unsigned short* wtm2 = (unsigned short*)(ws + 10*MB);   // 2 MB
  float* bqkv = (float*)(ws + 12*MB);                     // 12 KB
  float* mbuf = (float*)(ws + 12*MB + 256*1024);          // 256 KB
  float* lbuf = (float*)(ws + 12*MB + 512*1024);          // 256 KB
  unsigned short* o    = (unsigned short*)(ws + 13*MB);   // 8 MB (later: ctx)
  unsigned short* qh   = (unsigned short*)(ws + 21*MB);   // 8 MB (later: h1)
  unsigned short* kh   = (unsigned short*)(ws + 29*MB);   // 8 MB
  unsigned short* vt   = (unsigned short*)(ws + 37*MB);   // 8 MB (later: hin)
  float* x2            = (float*)(ws + 45*MB);            // 16 MB
  unsigned short* ctx  = o;     // o dead after gemm_qkv
  unsigned short* hin  = vt;    // vt dead after flash
  unsigned short* h1   = qh;    // qh dead after amean

  float* outX = (float*)d_out;
  float* outA = outX + (size_t)2*2048*1024;

  dim3 tt(32, 8);
  transpose_w<<<dim3(32,32), tt, 0, stream>>>(Wq,  wqkv);
  transpose_w<<<dim3(32,32), tt, 0, stream>>>(Wk,  wqkv + 1024*1024);
  transpose_w<<<dim3(32,32), tt, 0, stream>>>(Wv,  wqkv + 2*1024*1024);
  transpose_w<<<dim3(32,32), tt, 0, stream>>>(Wo,  wto);
  transpose_w<<<dim3(32,32), tt, 0, stream>>>(Wm1, wtm1);
  transpose_w<<<dim3(32,32), tt, 0, stream>>>(Wm2, wtm2);
  concat_bias<<<12, 256, 0, stream>>>(bq, bk, bv, bqkv);

  ln_kernel<<<4096, 256, 0, stream>>>(x, g1, b1, o);
  gemm_qkv<<<dim3(24,32), 256, 0, stream>>>(o, wqkv, bqkv, qh, kh, vt);

  flash_kernel<<<dim3(32,32), 256, 0, stream>>>(qh, kh, vt, ctx, mbuf, lbuf);
  amean_kernel<<<dim3(32,32,2), 256, 0, stream>>>(qh, kh, mbuf, lbuf, outA);

  gemm_bt<2><<<dim3(8,32), 256, 0, stream>>>(ctx, wto, bo, x, (void*)x2);
  ln_kernel<<<4096, 256, 0, stream>>>(x2, g2, b2, hin);
  gemm_bt<1><<<dim3(8,32), 256, 0, stream>>>(hin, wtm1, bm1, nullptr, h1);
  gemm_bt<2><<<dim3(8,32), 256, 0, stream>>>(h1, wtm2, bm2, x2, (void*)outX);
}

// Round 5
// 423.202 us; speedup vs baseline: 1.2829x; 1.2829x over previous
//
#include <hip/hip_runtime.h>
#include <hip/hip_bf16.h>
#include <cstdint>
#include <cstddef>

#define DEVI __device__ __forceinline__

typedef __attribute__((ext_vector_type(8))) short bf16x8;
typedef __attribute__((ext_vector_type(4))) float f32x4;

DEVI unsigned short f2bf(float f){
  unsigned u; __builtin_memcpy(&u, &f, 4);
  u += 0x7fffu + ((u >> 16) & 1u);
  return (unsigned short)(u >> 16);
}

DEVI f32x4 mfma_bf16(bf16x8 a, bf16x8 b, f32x4 c){
  return __builtin_amdgcn_mfma_f32_16x16x32_bf16(a, b, c, 0, 0, 0);
}

DEVI float exp2fast(float x){ return __builtin_amdgcn_exp2f(x); }

#define GLDS16(gp, lp) __builtin_amdgcn_global_load_lds( \
    (const __attribute__((address_space(1))) void*)(gp), \
    (__attribute__((address_space(3))) void*)(lp), 16, 0, 0)

// ---------------------------------------------------------------------------
// Batched: 6x { W fp32 [K=1024][N=1024] -> Wt bf16 [N][K] }
__global__ __launch_bounds__(256) void transpose_all(
    const float* __restrict__ W0, const float* __restrict__ W1,
    const float* __restrict__ W2, const float* __restrict__ W3,
    const float* __restrict__ W4, const float* __restrict__ W5,
    unsigned short* __restrict__ D0, unsigned short* __restrict__ D1,
    unsigned short* __restrict__ D2, unsigned short* __restrict__ D3,
    unsigned short* __restrict__ D4, unsigned short* __restrict__ D5){
  const float* W; unsigned short* D;
  switch (blockIdx.z){
    case 0: W = W0; D = D0; break;
    case 1: W = W1; D = D1; break;
    case 2: W = W2; D = D2; break;
    case 3: W = W3; D = D3; break;
    case 4: W = W4; D = D4; break;
    default: W = W5; D = D5; break;
  }
  __shared__ float tile[32][33];
  int bx = blockIdx.x * 32;  // n block
  int by = blockIdx.y * 32;  // k block
  int tx = threadIdx.x, ty = threadIdx.y;
  #pragma unroll
  for (int j = 0; j < 32; j += 8)
    tile[ty + j][tx] = W[(size_t)(by + ty + j) * 1024 + bx + tx];
  __syncthreads();
  #pragma unroll
  for (int j = 0; j < 32; j += 8)
    D[(size_t)(bx + ty + j) * 1024 + by + tx] = f2bf(tile[tx][ty + j]);
}

__global__ __launch_bounds__(256) void concat_bias(const float* __restrict__ a,
                                                   const float* __restrict__ b,
                                                   const float* __restrict__ c,
                                                   float* __restrict__ o){
  int i = blockIdx.x * 256 + threadIdx.x;
  o[i] = (i < 1024) ? a[i] : ((i < 2048) ? b[i - 1024] : c[i - 2048]);
}

// ---------------------------------------------------------------------------
// LayerNorm: fp32 row[1024] -> bf16 row
__global__ __launch_bounds__(256) void ln_kernel(const float* __restrict__ x,
                                                 const float* __restrict__ g,
                                                 const float* __restrict__ b,
                                                 unsigned short* __restrict__ out){
  int row = blockIdx.x, t = threadIdx.x, lane = t & 63, wid = t >> 6;
  const float4* xr = (const float4*)(x + (size_t)row * 1024);
  float4 v = xr[t];
  float s = v.x + v.y + v.z + v.w;
  #pragma unroll
  for (int o = 32; o >= 1; o >>= 1) s += __shfl_xor(s, o, 64);
  __shared__ float red[8];
  if (lane == 0) red[wid] = s;
  __syncthreads();
  float mu = (red[0] + red[1] + red[2] + red[3]) * (1.0f / 1024.0f);
  float d0 = v.x - mu, d1 = v.y - mu, d2 = v.z - mu, d3 = v.w - mu;
  float ss = d0*d0 + d1*d1 + d2*d2 + d3*d3;
  #pragma unroll
  for (int o = 32; o >= 1; o >>= 1) ss += __shfl_xor(ss, o, 64);
  if (lane == 0) red[4 + wid] = ss;
  __syncthreads();
  float var = (red[4] + red[5] + red[6] + red[7]) * (1.0f / 1024.0f);
  float rs = rsqrtf(var + 1e-5f);
  float4 gv = ((const float4*)g)[t];
  float4 bv = ((const float4*)b)[t];
  ushort4 o4;
  o4.x = f2bf(d0 * rs * gv.x + bv.x);
  o4.y = f2bf(d1 * rs * gv.y + bv.y);
  o4.z = f2bf(d2 * rs * gv.z + bv.z);
  o4.w = f2bf(d3 * rs * gv.w + bv.w);
  *(ushort4*)(out + (size_t)row * 1024 + t * 4) = o4;
}

// ---------------------------------------------------------------------------
// GEMM: A bf16 [M][1024] x Wt bf16 [N][1024]^T (+bias). EPI: 0=bf16 out,
// 1=gelu->bf16 out, 2=+res(fp32)->fp32 out.  m97 structure: 128x128, BK=32.
template<int EPI>
__global__ __launch_bounds__(256) void gemm_bt(const unsigned short* __restrict__ A,
                                               const unsigned short* __restrict__ Bt,
                                               const float* __restrict__ bias,
                                               const float* __restrict__ res,
                                               void* __restrict__ outp){
  const int K = 1024, N = 1024;
  __shared__ short As[128 * 32];
  __shared__ short Bs[128 * 32];
  int t = threadIdx.x, lane = t & 63, w = t >> 6;
  int wm = w >> 1, wn = w & 1;
  int m0 = blockIdx.y * 128, n0 = blockIdx.x * 128;
  f32x4 acc[4][4] = {};
  for (int k0 = 0; k0 < K; k0 += 32){
    __syncthreads();
    #pragma unroll
    for (int j = 0; j < 2; j++){
      int c = t + j * 256;
      int r = c >> 2, col = (c & 3) * 8;
      unsigned ldsb = (unsigned)(w * 1024 + j * 4096);
      GLDS16(A  + (size_t)(m0 + r) * K + k0 + col, (char*)As + ldsb);
      GLDS16(Bt + (size_t)(n0 + r) * K + k0 + col, (char*)Bs + ldsb);
    }
    __syncthreads();
    bf16x8 af[4], bf[4];
    #pragma unroll
    for (int mi = 0; mi < 4; mi++)
      af[mi] = *(const bf16x8*)(As + (wm*64 + mi*16 + (lane & 15)) * 32 + (lane >> 4) * 8);
    #pragma unroll
    for (int ni = 0; ni < 4; ni++)
      bf[ni] = *(const bf16x8*)(Bs + (wn*64 + ni*16 + (lane & 15)) * 32 + (lane >> 4) * 8);
    #pragma unroll
    for (int mi = 0; mi < 4; mi++)
      #pragma unroll
      for (int ni = 0; ni < 4; ni++)
        acc[mi][ni] = mfma_bf16(af[mi], bf[ni], acc[mi][ni]);
  }
  #pragma unroll
  for (int mi = 0; mi < 4; mi++){
    #pragma unroll
    for (int ni = 0; ni < 4; ni++){
      #pragma unroll
      for (int r = 0; r < 4; r++){
        int row = m0 + wm*64 + mi*16 + ((lane >> 4) << 2) + r;
        int col = n0 + wn*64 + ni*16 + (lane & 15);
        float v = acc[mi][ni][r] + bias[col];
        if (EPI == 1) v = 0.5f * v * (1.0f + erff(v * 0.70710678118654752f));
        if (EPI == 2){
          v += res[(size_t)row * N + col];
          ((float*)outp)[(size_t)row * N + col] = v;
        } else {
          ((unsigned short*)outp)[(size_t)row * N + col] = f2bf(v);
        }
      }
    }
  }
}

// ---------------------------------------------------------------------------
// Fused QKV GEMM: A bf16 [4096][1024] x WQKV bf16 [3072][1024]^T + bias.
// Writes q,k head-major [b][h][s][64] and v transposed [b][h][64][s].
__global__ __launch_bounds__(256) void gemm_qkv(const unsigned short* __restrict__ A,
                                                const unsigned short* __restrict__ Bt,
                                                const float* __restrict__ bias,
                                                unsigned short* __restrict__ qh,
                                                unsigned short* __restrict__ kh,
                                                unsigned short* __restrict__ vt){
  const int K = 1024;
  __shared__ short As[128 * 32];
  __shared__ short Bs[128 * 32];
  int t = threadIdx.x, lane = t & 63, w = t >> 6;
  int wm = w >> 1, wn = w & 1;
  int m0 = blockIdx.y * 128, n0 = blockIdx.x * 128;
  f32x4 acc[4][4] = {};
  for (int k0 = 0; k0 < K; k0 += 32){
    __syncthreads();
    #pragma unroll
    for (int j = 0; j < 2; j++){
      int c = t + j * 256;
      int r = c >> 2, col = (c & 3) * 8;
      unsigned ldsb = (unsigned)(w * 1024 + j * 4096);
      GLDS16(A  + (size_t)(m0 + r) * K + k0 + col, (char*)As + ldsb);
      GLDS16(Bt + (size_t)(n0 + r) * K + k0 + col, (char*)Bs + ldsb);
    }
    __syncthreads();
    bf16x8 af[4], bf[4];
    #pragma unroll
    for (int mi = 0; mi < 4; mi++)
      af[mi] = *(const bf16x8*)(As + (wm*64 + mi*16 + (lane & 15)) * 32 + (lane >> 4) * 8);
    #pragma unroll
    for (int ni = 0; ni < 4; ni++)
      bf[ni] = *(const bf16x8*)(Bs + (wn*64 + ni*16 + (lane & 15)) * 32 + (lane >> 4) * 8);
    #pragma unroll
    for (int mi = 0; mi < 4; mi++)
      #pragma unroll
      for (int ni = 0; ni < 4; ni++)
        acc[mi][ni] = mfma_bf16(af[mi], bf[ni], acc[mi][ni]);
  }
  int ln15 = lane & 15, g = lane >> 4;
  #pragma unroll
  for (int mi = 0; mi < 4; mi++){
    #pragma unroll
    for (int ni = 0; ni < 4; ni++){
      int cnb = n0 + wn*64 + ni*16;            // frag col base (wave-uniform)
      int sel = cnb >> 10;
      int hh = (cnb & 1023) >> 6;
      int d = (cnb & 63) + ln15;
      int row0 = m0 + wm*64 + mi*16 + g*4;
      int b = row0 >> 11, s0 = row0 & 2047;
      float v4[4];
      #pragma unroll
      for (int r = 0; r < 4; r++) v4[r] = acc[mi][ni][r] + bias[cnb + ln15];
      if (sel == 2){
        ushort4 u;
        u.x = f2bf(v4[0]); u.y = f2bf(v4[1]); u.z = f2bf(v4[2]); u.w = f2bf(v4[3]);
        *(ushort4*)(vt + ((size_t)(b*16 + hh)*64 + d)*2048 + s0) = u;
      } else {
        unsigned short* dst = (sel == 0) ? qh : kh;
        #pragma unroll
        for (int r = 0; r < 4; r++)
          dst[((size_t)(b*16 + hh)*2048 + s0 + r)*64 + d] = f2bf(v4[r]);
      }
    }
  }
}

// ---------------------------------------------------------------------------
// Flash attention, swapped operands, zero barriers, direct global frag loads.
__global__ __launch_bounds__(256) void flash_kernel(const unsigned short* __restrict__ Qh,
                                                    const unsigned short* __restrict__ Kh,
                                                    const unsigned short* __restrict__ Vt,
                                                    unsigned short* __restrict__ CTX,
                                                    float* __restrict__ Mo,
                                                    float* __restrict__ Lo){
  const float SC = 0.18033688011112042f;   // log2(e)/8
  int qt = 31 - blockIdx.y;
  int h = blockIdx.x >> 1, b = blockIdx.x & 1;
  int bh = b * 16 + h;
  int t = threadIdx.x, lane = t & 63, w = t >> 6;
  int ln15 = lane & 15, g = lane >> 4;
  int q = qt * 64 + w * 16 + ln15;         // this lane's q row (B/C col index)
  __shared__ short Ps[4][16][80];          // wave-private P tile, stride 160B

  const unsigned short* qp = Qh + ((size_t)bh * 2048 + q) * 64 + g * 8;
  bf16x8 bq0 = *(const bf16x8*)(qp);
  bf16x8 bq1 = *(const bf16x8*)(qp + 32);
  f32x4 acc[4] = {};
  float m2 = -1e30f, l = 0.f;

  for (int kt = 0; kt <= qt; kt++){
    const unsigned short* kp = Kh + ((size_t)bh * 2048 + kt * 64 + ln15) * 64 + g * 8;
    // scores^T = K * Q : out[m=kcol][n=q]
    f32x4 sf[4];
    #pragma unroll
    for (int kf = 0; kf < 4; kf++){
      bf16x8 a0 = *(const bf16x8*)(kp + (size_t)kf * 16 * 64);
      bf16x8 a1 = *(const bf16x8*)(kp + (size_t)kf * 16 * 64 + 32);
      f32x4 z = {};
      z = mfma_bf16(a0, bq0, z);
      z = mfma_bf16(a1, bq1, z);
      sf[kf] = z;
    }
    float s2[16];
    bool diag = (kt == qt);
    #pragma unroll
    for (int kf = 0; kf < 4; kf++)
      #pragma unroll
      for (int r = 0; r < 4; r++){
        float v = sf[kf][r] * SC;
        if (diag && (kt * 64 + kf * 16 + g * 4 + r > q)) v = -1e30f;
        s2[kf * 4 + r] = v;
      }
    float tm = s2[0];
    #pragma unroll
    for (int i = 1; i < 16; i++) tm = fmaxf(tm, s2[i]);
    tm = fmaxf(tm, __shfl_xor(tm, 16, 64));
    tm = fmaxf(tm, __shfl_xor(tm, 32, 64));
    if (!__all(tm <= m2 + 8.0f)){          // T13 defer-max
      float mn = fmaxf(m2, tm);
      float sc = exp2fast(m2 - mn);
      l *= sc;
      #pragma unroll
      for (int df = 0; df < 4; df++)
        #pragma unroll
        for (int r = 0; r < 4; r++) acc[df][r] *= sc;
      m2 = mn;
    }
    float p[16], ps = 0.f;
    #pragma unroll
    for (int i = 0; i < 16; i++){ p[i] = exp2fast(s2[i] - m2); ps += p[i]; }
    ps += __shfl_xor(ps, 16, 64);
    ps += __shfl_xor(ps, 32, 64);
    l += ps;
    // pack P -> wave-private LDS (row = q-local = ln15, col = kcol-local)
    #pragma unroll
    for (int kf = 0; kf < 4; kf++){
      ushort4 u;
      u.x = f2bf(p[kf*4+0]); u.y = f2bf(p[kf*4+1]);
      u.z = f2bf(p[kf*4+2]); u.w = f2bf(p[kf*4+3]);
      *(ushort4*)&Ps[w][ln15][kf * 16 + g * 4] = u;
    }
    bf16x8 bp0 = *(const bf16x8*)&Ps[w][ln15][g * 8];
    bf16x8 bp1 = *(const bf16x8*)&Ps[w][ln15][32 + g * 8];
    // ctx^T += V^T * P : out[m=d][n=q]
    const unsigned short* vp = Vt + ((size_t)bh * 64 + ln15) * 2048 + kt * 64 + g * 8;
    #pragma unroll
    for (int df = 0; df < 4; df++){
      bf16x8 a0 = *(const bf16x8*)(vp + (size_t)df * 16 * 2048);
      bf16x8 a1 = *(const bf16x8*)(vp + (size_t)df * 16 * 2048 + 32);
      acc[df] = mfma_bf16(a0, bp0, acc[df]);
      acc[df] = mfma_bf16(a1, bp1, acc[df]);
    }
  }
  float inv = 1.0f / l;
  #pragma unroll
  for (int df = 0; df < 4; df++){
    ushort4 u;
    u.x = f2bf(acc[df][0] * inv); u.y = f2bf(acc[df][1] * inv);
    u.z = f2bf(acc[df][2] * inv); u.w = f2bf(acc[df][3] * inv);
    *(ushort4*)(CTX + ((size_t)(b * 2048 + q)) * 1024 + h * 64 + df * 16 + g * 4) = u;
  }
  if (g == 0){
    Mo[(size_t)bh * 2048 + q] = m2;
    Lo[(size_t)bh * 2048 + q] = inv;       // store 1/l for amean
  }
}

// ---------------------------------------------------------------------------
// Stage one 64x128B tile (K or Q) into LDS with XOR-swizzled SOURCE cols so
// ds_read_b128 frags are conflict-free (rule #21: linear dest + pre-swz src).
DEVI void stage_tile(const unsigned short* __restrict__ src, short* dst, int t){
  #pragma unroll
  for (int j = 0; j < 2; j++){
    int c = t + j * 256;                   // chunk 0..511 (16B each)
    int r = c >> 3;                        // row 0..63
    int cs = ((c & 7) * 16) ^ ((r & 7) << 4);
    GLDS16(src + (size_t)r * 64 + (cs >> 1),
           (char*)dst + (unsigned)((t >> 6) * 1024 + j * 4096));
  }
}

// Head-averaged attention probabilities: LDS double-buffered per-head staging.
__global__ __launch_bounds__(256) void amean_kernel(const unsigned short* __restrict__ Qh,
                                                    const unsigned short* __restrict__ Kh,
                                                    const float* __restrict__ Mo,
                                                    const float* __restrict__ Lo,
                                                    float* __restrict__ outA){
  const float SC = 0.18033688011112042f;
  int kt = blockIdx.x, qt = blockIdx.y, b = blockIdx.z;
  int q0 = qt * 64, k0 = kt * 64;
  int t = threadIdx.x;
  if (kt > qt){
    float4 z = {0.f, 0.f, 0.f, 0.f};
    #pragma unroll
    for (int i = 0; i < 4; i++){
      int c = t + i * 256; int r = c >> 4, col = (c & 15) * 4;
      *(float4*)(outA + (size_t)(b*2048 + q0 + r) * 2048 + k0 + col) = z;
    }
    return;
  }
  __shared__ __align__(16) short Kb[2][4096];
  __shared__ __align__(16) short Qb[2][4096];
  int lane = t & 63, w = t >> 6, ln15 = lane & 15, g = lane >> 4;
  int qc0 = q0 + w * 16 + g * 4;           // this lane's 4 output q rows
  int qrow = w * 16 + ln15;                // local q row for B-frag
  int qsw = (ln15 & 7) << 4;
  bool diag = (kt == qt);
  f32x4 am[4] = {};

  stage_tile(Kh + ((size_t)(b*16) * 2048 + k0) * 64, Kb[0], t);
  stage_tile(Qh + ((size_t)(b*16) * 2048 + q0) * 64, Qb[0], t);
  __syncthreads();

  for (int h = 0; h < 16; h++){
    int par = h & 1;
    if (h + 1 < 16){
      size_t bh1 = (size_t)(b*16 + h + 1);
      stage_tile(Kh + (bh1 * 2048 + k0) * 64, Kb[par ^ 1], t);
      stage_tile(Qh + (bh1 * 2048 + q0) * 64, Qb[par ^ 1], t);
    }
    size_t bh = (size_t)(b*16 + h);
    f32x4 mh = *(const f32x4*)&Mo[bh * 2048 + qc0];
    f32x4 li = *(const f32x4*)&Lo[bh * 2048 + qc0];
    const char* qbase = (const char*)Qb[par] + qrow * 128;
    bf16x8 qb0 = *(const bf16x8*)(qbase + ((g*16)      ^ qsw));
    bf16x8 qb1 = *(const bf16x8*)(qbase + ((g*16 + 64) ^ qsw));
    #pragma unroll
    for (int kf = 0; kf < 4; kf++){
      const char* kbase = (const char*)Kb[par] + (kf*16 + ln15) * 128;
      bf16x8 ka0 = *(const bf16x8*)(kbase + ((g*16)      ^ qsw));
      bf16x8 ka1 = *(const bf16x8*)(kbase + ((g*16 + 64) ^ qsw));
      f32x4 z = {};
      z = mfma_bf16(ka0, qb0, z);
      z = mfma_bf16(ka1, qb1, z);
      #pragma unroll
      for (int r = 0; r < 4; r++){
        float a = exp2fast(z[r] * SC - mh[r]) * li[r];
        if (diag && (k0 + kf * 16 + ln15 > qc0 + r)) a = 0.f;
        am[kf][r] += a;
      }
    }
    __syncthreads();                       // drains vmcnt(0): stage(h+1) done
  }
  #pragma unroll
  for (int kf = 0; kf < 4; kf++)
    #pragma unroll
    for (int r = 0; r < 4; r++)
      outA[(size_t)(b*2048 + qc0 + r) * 2048 + k0 + kf * 16 + ln15] = am[kf][r] * 0.0625f;
}

// ---------------------------------------------------------------------------
extern "C" void kernel_launch(void* const* d_in, const int* in_sizes, int n_in,
                              void* d_out, int out_size, void* d_ws, size_t ws_size,
                              hipStream_t stream){
  const float* x   = (const float*)d_in[0];
  const float* Wq  = (const float*)d_in[1];
  const float* bq  = (const float*)d_in[2];
  const float* Wk  = (const float*)d_in[3];
  const float* bk  = (const float*)d_in[4];
  const float* Wv  = (const float*)d_in[5];
  const float* bv  = (const float*)d_in[6];
  const float* Wo  = (const float*)d_in[7];
  const float* bo  = (const float*)d_in[8];
  const float* g1  = (const float*)d_in[9];
  const float* b1  = (const float*)d_in[10];
  const float* g2  = (const float*)d_in[11];
  const float* b2  = (const float*)d_in[12];
  const float* Wm1 = (const float*)d_in[13];
  const float* bm1 = (const float*)d_in[14];
  const float* Wm2 = (const float*)d_in[15];
  const float* bm2 = (const float*)d_in[16];

  char* ws = (char*)d_ws;
  const size_t MB = (size_t)1 << 20;
  unsigned short* wqkv = (unsigned short*)(ws + 0*MB);    // 6 MB
  unsigned short* wto  = (unsigned short*)(ws + 6*MB);    // 2 MB
  unsigned short* wtm1 = (unsigned short*)(ws + 8*MB);    // 2 MB
  unsigned short* wtm2 = (unsigned short*)(ws + 10*MB);   // 2 MB
  float* bqkv = (float*)(ws + 12*MB);                     // 12 KB
  float* mbuf = (float*)(ws + 12*MB + 256*1024);          // 256 KB
  float* lbuf = (float*)(ws + 12*MB + 512*1024);          // 256 KB
  unsigned short* o    = (unsigned short*)(ws + 13*MB);   // 8 MB (later: ctx)
  unsigned short* qh   = (unsigned short*)(ws + 21*MB);   // 8 MB (later: h1)
  unsigned short* kh   = (unsigned short*)(ws + 29*MB);   // 8 MB
  unsigned short* vt   = (unsigned short*)(ws + 37*MB);   // 8 MB (later: hin)
  float* x2            = (float*)(ws + 45*MB);            // 16 MB
  unsigned short* ctx  = o;     // o dead after gemm_qkv
  unsigned short* hin  = vt;    // vt dead after flash
  unsigned short* h1   = qh;    // qh dead after amean

  float* outX = (float*)d_out;
  float* outA = outX + (size_t)2*2048*1024;

  transpose_all<<<dim3(32,32,6), dim3(32,8), 0, stream>>>(
      Wq, Wk, Wv, Wo, Wm1, Wm2,
      wqkv, wqkv + 1024*1024, wqkv + 2*1024*1024, wto, wtm1, wtm2);
  concat_bias<<<12, 256, 0, stream>>>(bq, bk, bv, bqkv);

  ln_kernel<<<4096, 256, 0, stream>>>(x, g1, b1, o);
  gemm_qkv<<<dim3(24,32), 256, 0, stream>>>(o, wqkv, bqkv, qh, kh, vt);

  flash_kernel<<<dim3(32,32), 256, 0, stream>>>(qh, kh, vt, ctx, mbuf, lbuf);
  amean_kernel<<<dim3(32,32,2), 256, 0, stream>>>(qh, kh, mbuf, lbuf, outA);

  gemm_bt<2><<<dim3(8,32), 256, 0, stream>>>(ctx, wto, bo, x, (void*)x2);
  ln_kernel<<<4096, 256, 0, stream>>>(x2, g2, b2, hin);
  gemm_bt<1><<<dim3(8,32), 256, 0, stream>>>(hin, wtm1, bm1, nullptr, h1);
  gemm_bt<2><<<dim3(8,32), 256, 0, stream>>>(h1, wtm2, bm2, x2, (void*)outX);
}

// Round 6
// 322.502 us; speedup vs baseline: 1.6835x; 1.3122x over previous
//
#include <hip/hip_runtime.h>
#include <hip/hip_bf16.h>
#include <cstdint>
#include <cstddef>

#define DEVI __device__ __forceinline__

typedef __attribute__((ext_vector_type(8))) short bf16x8;
typedef __attribute__((ext_vector_type(4))) float f32x4;

DEVI unsigned short f2bf(float f){
  unsigned u; __builtin_memcpy(&u, &f, 4);
  u += 0x7fffu + ((u >> 16) & 1u);
  return (unsigned short)(u >> 16);
}

DEVI f32x4 mfma_bf16(bf16x8 a, bf16x8 b, f32x4 c){
  return __builtin_amdgcn_mfma_f32_16x16x32_bf16(a, b, c, 0, 0, 0);
}

DEVI float exp2fast(float x){ return __builtin_amdgcn_exp2f(x); }

#define GLDS16(gp, lp) __builtin_amdgcn_global_load_lds( \
    (const __attribute__((address_space(1))) void*)(gp), \
    (__attribute__((address_space(3))) void*)(lp), 16, 0, 0)

// ---------------------------------------------------------------------------
// Stage one 64-row x 128B tile into LDS, row-chunk XOR-swizzled via the
// SOURCE address (rule #21: global_load_lds writes linearly; pre-swizzle the
// per-lane global source, apply the same XOR on ds_read). rstride = row
// stride of the source in elements.
DEVI void stage_swz(const unsigned short* __restrict__ src, size_t rstride,
                    short* dst, int t){
  #pragma unroll
  for (int j = 0; j < 2; j++){
    int c = t + j * 256;                   // LDS chunk slot 0..511 (16B each)
    int r = c >> 3;                        // row 0..63
    int cc = (c & 7) ^ (r & 7);            // source column chunk
    GLDS16(src + (size_t)r * rstride + cc * 8,
           (char*)dst + (unsigned)((t >> 6) * 1024 + j * 4096));
  }
}

// ---------------------------------------------------------------------------
// Batched: 6x { W fp32 [K=1024][N=1024] -> Wt bf16 [N][K] }
__global__ __launch_bounds__(256) void transpose_all(
    const float* __restrict__ W0, const float* __restrict__ W1,
    const float* __restrict__ W2, const float* __restrict__ W3,
    const float* __restrict__ W4, const float* __restrict__ W5,
    unsigned short* __restrict__ D0, unsigned short* __restrict__ D1,
    unsigned short* __restrict__ D2, unsigned short* __restrict__ D3,
    unsigned short* __restrict__ D4, unsigned short* __restrict__ D5){
  const float* W; unsigned short* D;
  switch (blockIdx.z){
    case 0: W = W0; D = D0; break;
    case 1: W = W1; D = D1; break;
    case 2: W = W2; D = D2; break;
    case 3: W = W3; D = D3; break;
    case 4: W = W4; D = D4; break;
    default: W = W5; D = D5; break;
  }
  __shared__ float tile[32][33];
  int bx = blockIdx.x * 32;  // n block
  int by = blockIdx.y * 32;  // k block
  int tx = threadIdx.x, ty = threadIdx.y;
  #pragma unroll
  for (int j = 0; j < 32; j += 8)
    tile[ty + j][tx] = W[(size_t)(by + ty + j) * 1024 + bx + tx];
  __syncthreads();
  #pragma unroll
  for (int j = 0; j < 32; j += 8)
    D[(size_t)(bx + ty + j) * 1024 + by + tx] = f2bf(tile[tx][ty + j]);
}

__global__ __launch_bounds__(256) void concat_bias(const float* __restrict__ a,
                                                   const float* __restrict__ b,
                                                   const float* __restrict__ c,
                                                   float* __restrict__ o){
  int i = blockIdx.x * 256 + threadIdx.x;
  o[i] = (i < 1024) ? a[i] : ((i < 2048) ? b[i - 1024] : c[i - 2048]);
}

// ---------------------------------------------------------------------------
// LayerNorm: fp32 row[1024] -> bf16 row
__global__ __launch_bounds__(256) void ln_kernel(const float* __restrict__ x,
                                                 const float* __restrict__ g,
                                                 const float* __restrict__ b,
                                                 unsigned short* __restrict__ out){
  int row = blockIdx.x, t = threadIdx.x, lane = t & 63, wid = t >> 6;
  const float4* xr = (const float4*)(x + (size_t)row * 1024);
  float4 v = xr[t];
  float s = v.x + v.y + v.z + v.w;
  #pragma unroll
  for (int o = 32; o >= 1; o >>= 1) s += __shfl_xor(s, o, 64);
  __shared__ float red[8];
  if (lane == 0) red[wid] = s;
  __syncthreads();
  float mu = (red[0] + red[1] + red[2] + red[3]) * (1.0f / 1024.0f);
  float d0 = v.x - mu, d1 = v.y - mu, d2 = v.z - mu, d3 = v.w - mu;
  float ss = d0*d0 + d1*d1 + d2*d2 + d3*d3;
  #pragma unroll
  for (int o = 32; o >= 1; o >>= 1) ss += __shfl_xor(ss, o, 64);
  if (lane == 0) red[4 + wid] = ss;
  __syncthreads();
  float var = (red[4] + red[5] + red[6] + red[7]) * (1.0f / 1024.0f);
  float rs = rsqrtf(var + 1e-5f);
  float4 gv = ((const float4*)g)[t];
  float4 bv = ((const float4*)b)[t];
  ushort4 o4;
  o4.x = f2bf(d0 * rs * gv.x + bv.x);
  o4.y = f2bf(d1 * rs * gv.y + bv.y);
  o4.z = f2bf(d2 * rs * gv.z + bv.z);
  o4.w = f2bf(d3 * rs * gv.w + bv.w);
  *(ushort4*)(out + (size_t)row * 1024 + t * 4) = o4;
}

// ---------------------------------------------------------------------------
// GEMM: A bf16 [M][1024] x Wt bf16 [N][1024]^T (+bias). EPI: 0=bf16 out,
// 1=gelu->bf16 out, 2=+res(fp32)->fp32 out.  m97 structure: 128x128, BK=32.
template<int EPI>
__global__ __launch_bounds__(256) void gemm_bt(const unsigned short* __restrict__ A,
                                               const unsigned short* __restrict__ Bt,
                                               const float* __restrict__ bias,
                                               const float* __restrict__ res,
                                               void* __restrict__ outp){
  const int K = 1024, N = 1024;
  __shared__ short As[128 * 32];
  __shared__ short Bs[128 * 32];
  int t = threadIdx.x, lane = t & 63, w = t >> 6;
  int wm = w >> 1, wn = w & 1;
  int m0 = blockIdx.y * 128, n0 = blockIdx.x * 128;
  f32x4 acc[4][4] = {};
  for (int k0 = 0; k0 < K; k0 += 32){
    __syncthreads();
    #pragma unroll
    for (int j = 0; j < 2; j++){
      int c = t + j * 256;
      int r = c >> 2, col = (c & 3) * 8;
      unsigned ldsb = (unsigned)(w * 1024 + j * 4096);
      GLDS16(A  + (size_t)(m0 + r) * K + k0 + col, (char*)As + ldsb);
      GLDS16(Bt + (size_t)(n0 + r) * K + k0 + col, (char*)Bs + ldsb);
    }
    __syncthreads();
    bf16x8 af[4], bf[4];
    #pragma unroll
    for (int mi = 0; mi < 4; mi++)
      af[mi] = *(const bf16x8*)(As + (wm*64 + mi*16 + (lane & 15)) * 32 + (lane >> 4) * 8);
    #pragma unroll
    for (int ni = 0; ni < 4; ni++)
      bf[ni] = *(const bf16x8*)(Bs + (wn*64 + ni*16 + (lane & 15)) * 32 + (lane >> 4) * 8);
    #pragma unroll
    for (int mi = 0; mi < 4; mi++)
      #pragma unroll
      for (int ni = 0; ni < 4; ni++)
        acc[mi][ni] = mfma_bf16(af[mi], bf[ni], acc[mi][ni]);
  }
  #pragma unroll
  for (int mi = 0; mi < 4; mi++){
    #pragma unroll
    for (int ni = 0; ni < 4; ni++){
      #pragma unroll
      for (int r = 0; r < 4; r++){
        int row = m0 + wm*64 + mi*16 + ((lane >> 4) << 2) + r;
        int col = n0 + wn*64 + ni*16 + (lane & 15);
        float v = acc[mi][ni][r] + bias[col];
        if (EPI == 1) v = 0.5f * v * (1.0f + erff(v * 0.70710678118654752f));
        if (EPI == 2){
          v += res[(size_t)row * N + col];
          ((float*)outp)[(size_t)row * N + col] = v;
        } else {
          ((unsigned short*)outp)[(size_t)row * N + col] = f2bf(v);
        }
      }
    }
  }
}

// ---------------------------------------------------------------------------
// Fused QKV GEMM: A bf16 [4096][1024] x WQKV bf16 [3072][1024]^T + bias.
// Writes q,k head-major [b][h][s][64] and v transposed [b][h][64][s].
__global__ __launch_bounds__(256) void gemm_qkv(const unsigned short* __restrict__ A,
                                                const unsigned short* __restrict__ Bt,
                                                const float* __restrict__ bias,
                                                unsigned short* __restrict__ qh,
                                                unsigned short* __restrict__ kh,
                                                unsigned short* __restrict__ vt){
  const int K = 1024;
  __shared__ short As[128 * 32];
  __shared__ short Bs[128 * 32];
  int t = threadIdx.x, lane = t & 63, w = t >> 6;
  int wm = w >> 1, wn = w & 1;
  int m0 = blockIdx.y * 128, n0 = blockIdx.x * 128;
  f32x4 acc[4][4] = {};
  for (int k0 = 0; k0 < K; k0 += 32){
    __syncthreads();
    #pragma unroll
    for (int j = 0; j < 2; j++){
      int c = t + j * 256;
      int r = c >> 2, col = (c & 3) * 8;
      unsigned ldsb = (unsigned)(w * 1024 + j * 4096);
      GLDS16(A  + (size_t)(m0 + r) * K + k0 + col, (char*)As + ldsb);
      GLDS16(Bt + (size_t)(n0 + r) * K + k0 + col, (char*)Bs + ldsb);
    }
    __syncthreads();
    bf16x8 af[4], bf[4];
    #pragma unroll
    for (int mi = 0; mi < 4; mi++)
      af[mi] = *(const bf16x8*)(As + (wm*64 + mi*16 + (lane & 15)) * 32 + (lane >> 4) * 8);
    #pragma unroll
    for (int ni = 0; ni < 4; ni++)
      bf[ni] = *(const bf16x8*)(Bs + (wn*64 + ni*16 + (lane & 15)) * 32 + (lane >> 4) * 8);
    #pragma unroll
    for (int mi = 0; mi < 4; mi++)
      #pragma unroll
      for (int ni = 0; ni < 4; ni++)
        acc[mi][ni] = mfma_bf16(af[mi], bf[ni], acc[mi][ni]);
  }
  int ln15 = lane & 15, g = lane >> 4;
  #pragma unroll
  for (int mi = 0; mi < 4; mi++){
    #pragma unroll
    for (int ni = 0; ni < 4; ni++){
      int cnb = n0 + wn*64 + ni*16;            // frag col base (wave-uniform)
      int sel = cnb >> 10;
      int hh = (cnb & 1023) >> 6;
      int d = (cnb & 63) + ln15;
      int row0 = m0 + wm*64 + mi*16 + g*4;
      int b = row0 >> 11, s0 = row0 & 2047;
      float v4[4];
      #pragma unroll
      for (int r = 0; r < 4; r++) v4[r] = acc[mi][ni][r] + bias[cnb + ln15];
      if (sel == 2){
        ushort4 u;
        u.x = f2bf(v4[0]); u.y = f2bf(v4[1]); u.z = f2bf(v4[2]); u.w = f2bf(v4[3]);
        *(ushort4*)(vt + ((size_t)(b*16 + hh)*64 + d)*2048 + s0) = u;
      } else {
        unsigned short* dst = (sel == 0) ? qh : kh;
        #pragma unroll
        for (int r = 0; r < 4; r++)
          dst[((size_t)(b*16 + hh)*2048 + s0 + r)*64 + d] = f2bf(v4[r]);
      }
    }
  }
}

// ---------------------------------------------------------------------------
// Flash attention v3: swapped operands + double-buffered LDS staging of K/V^T
// tiles (global_load_lds, pre-swizzled source), one barrier per kt iteration.
// Grid (32 bh, 32 qt reversed). 4 waves/block, wave w owns q rows qt*64+w*16..
__global__ __launch_bounds__(256) void flash_kernel(const unsigned short* __restrict__ Qh,
                                                    const unsigned short* __restrict__ Kh,
                                                    const unsigned short* __restrict__ Vt,
                                                    unsigned short* __restrict__ CTX,
                                                    float* __restrict__ Mo,
                                                    float* __restrict__ Lo){
  const float SC = 0.18033688011112042f;   // log2(e)/8
  int qt = 31 - blockIdx.y;
  int h = blockIdx.x >> 1, b = blockIdx.x & 1;
  int bh = b * 16 + h;
  int t = threadIdx.x, lane = t & 63, w = t >> 6;
  int ln15 = lane & 15, g = lane >> 4;
  int q = qt * 64 + w * 16 + ln15;         // this lane's q row (B/C col index)
  int sw = (ln15 & 7) << 4;                // read-side XOR (row&7, kf*16 ≡ 0 mod 8)

  __shared__ __align__(16) short Kb[2][4096];   // [64 s][64 d], swizzled
  __shared__ __align__(16) short Vb[2][4096];   // [64 d][64 s], swizzled
  __shared__ __align__(16) short Ps[4][16][72]; // wave-private P tile

  const unsigned short* qp = Qh + ((size_t)bh * 2048 + q) * 64 + g * 8;
  bf16x8 bq0 = *(const bf16x8*)(qp);
  bf16x8 bq1 = *(const bf16x8*)(qp + 32);
  f32x4 acc[4] = {};
  float m2 = -1e30f, l = 0.f;

  const unsigned short* Kbase = Kh + (size_t)bh * 2048 * 64;  // rows s, stride 64
  const unsigned short* Vbase = Vt + (size_t)bh * 64 * 2048;  // rows d, stride 2048

  stage_swz(Kbase, 64, Kb[0], t);
  stage_swz(Vbase, 2048, Vb[0], t);
  __syncthreads();

  for (int kt = 0; kt <= qt; kt++){
    int cur = kt & 1;
    if (kt < qt){                          // prefetch next tile (in flight across compute)
      stage_swz(Kbase + (size_t)(kt + 1) * 4096, 64, Kb[cur ^ 1], t);
      stage_swz(Vbase + (kt + 1) * 64, 2048, Vb[cur ^ 1], t);
    }
    // scores^T = K * Q : out[m=kcol][n=q]
    f32x4 sf[4];
    #pragma unroll
    for (int kf = 0; kf < 4; kf++){
      const char* kb = (const char*)Kb[cur] + (kf * 16 + ln15) * 128;
      bf16x8 a0 = *(const bf16x8*)(kb + ((g * 16) ^ sw));
      bf16x8 a1 = *(const bf16x8*)(kb + ((g * 16 + 64) ^ sw));
      f32x4 z = {};
      z = mfma_bf16(a0, bq0, z);
      z = mfma_bf16(a1, bq1, z);
      sf[kf] = z;
    }
    float s2[16];
    bool diag = (kt == qt);
    #pragma unroll
    for (int kf = 0; kf < 4; kf++)
      #pragma unroll
      for (int r = 0; r < 4; r++){
        float v = sf[kf][r] * SC;
        if (diag && (kt * 64 + kf * 16 + g * 4 + r > q)) v = -1e30f;
        s2[kf * 4 + r] = v;
      }
    // row max: depth-4 tree + 2 shfl (row lives in lanes {l, l^16, l^32, l^48})
    float mt[8];
    #pragma unroll
    for (int i = 0; i < 8; i++) mt[i] = fmaxf(s2[i], s2[i + 8]);
    #pragma unroll
    for (int i = 4; i >= 1; i >>= 1)
      #pragma unroll
      for (int j2 = 0; j2 < i; j2++) mt[j2] = fmaxf(mt[j2], mt[j2 + i]);
    float tm = mt[0];
    tm = fmaxf(tm, __shfl_xor(tm, 16, 64));
    tm = fmaxf(tm, __shfl_xor(tm, 32, 64));
    if (!__all(tm <= m2 + 8.0f)){          // T13 defer-max
      float mn = fmaxf(m2, tm);
      float sc = exp2fast(m2 - mn);
      l *= sc;
      #pragma unroll
      for (int df = 0; df < 4; df++)
        #pragma unroll
        for (int r = 0; r < 4; r++) acc[df][r] *= sc;
      m2 = mn;
    }
    float p[16];
    #pragma unroll
    for (int i = 0; i < 16; i++) p[i] = exp2fast(s2[i] - m2);
    float st[8];
    #pragma unroll
    for (int i = 0; i < 8; i++) st[i] = p[i] + p[i + 8];
    #pragma unroll
    for (int i = 4; i >= 1; i >>= 1)
      #pragma unroll
      for (int j2 = 0; j2 < i; j2++) st[j2] += st[j2 + i];
    float ps = st[0];
    ps += __shfl_xor(ps, 16, 64);
    ps += __shfl_xor(ps, 32, 64);
    l += ps;
    // pack P -> wave-private LDS (row = q-local = ln15, col = kcol-local)
    #pragma unroll
    for (int kf = 0; kf < 4; kf++){
      ushort4 u;
      u.x = f2bf(p[kf*4+0]); u.y = f2bf(p[kf*4+1]);
      u.z = f2bf(p[kf*4+2]); u.w = f2bf(p[kf*4+3]);
      *(ushort4*)&Ps[w][ln15][kf * 16 + g * 4] = u;
    }
    bf16x8 bp0 = *(const bf16x8*)&Ps[w][ln15][g * 8];
    bf16x8 bp1 = *(const bf16x8*)&Ps[w][ln15][32 + g * 8];
    // ctx^T += V^T * P : out[m=d][n=q]
    #pragma unroll
    for (int df = 0; df < 4; df++){
      const char* vb = (const char*)Vb[cur] + (df * 16 + ln15) * 128;
      bf16x8 a0 = *(const bf16x8*)(vb + ((g * 16) ^ sw));
      bf16x8 a1 = *(const bf16x8*)(vb + ((g * 16 + 64) ^ sw));
      acc[df] = mfma_bf16(a0, bp0, acc[df]);
      acc[df] = mfma_bf16(a1, bp1, acc[df]);
    }
    __syncthreads();                       // drains vmcnt (stage kt+1 done); buf safe to flip
  }
  float inv = 1.0f / l;
  #pragma unroll
  for (int df = 0; df < 4; df++){
    ushort4 u;
    u.x = f2bf(acc[df][0] * inv); u.y = f2bf(acc[df][1] * inv);
    u.z = f2bf(acc[df][2] * inv); u.w = f2bf(acc[df][3] * inv);
    *(ushort4*)(CTX + ((size_t)(b * 2048 + q)) * 1024 + h * 64 + df * 16 + g * 4) = u;
  }
  if (g == 0){
    Mo[(size_t)bh * 2048 + q] = m2;
    Lo[(size_t)bh * 2048 + q] = inv;       // store 1/l for amean
  }
}

// ---------------------------------------------------------------------------
// Head-averaged attention probabilities: LDS double-buffered per-head staging.
__global__ __launch_bounds__(256) void amean_kernel(const unsigned short* __restrict__ Qh,
                                                    const unsigned short* __restrict__ Kh,
                                                    const float* __restrict__ Mo,
                                                    const float* __restrict__ Lo,
                                                    float* __restrict__ outA){
  const float SC = 0.18033688011112042f;
  int kt = blockIdx.x, qt = blockIdx.y, b = blockIdx.z;
  int q0 = qt * 64, k0 = kt * 64;
  int t = threadIdx.x;
  if (kt > qt){
    float4 z = {0.f, 0.f, 0.f, 0.f};
    #pragma unroll
    for (int i = 0; i < 4; i++){
      int c = t + i * 256; int r = c >> 4, col = (c & 15) * 4;
      *(float4*)(outA + (size_t)(b*2048 + q0 + r) * 2048 + k0 + col) = z;
    }
    return;
  }
  __shared__ __align__(16) short Kb[2][4096];
  __shared__ __align__(16) short Qb[2][4096];
  int lane = t & 63, w = t >> 6, ln15 = lane & 15, g = lane >> 4;
  int qc0 = q0 + w * 16 + g * 4;           // this lane's 4 output q rows
  int qrow = w * 16 + ln15;                // local q row for B-frag
  int qsw = (ln15 & 7) << 4;
  bool diag = (kt == qt);
  f32x4 am[4] = {};

  stage_swz(Kh + ((size_t)(b*16) * 2048 + k0) * 64, 64, Kb[0], t);
  stage_swz(Qh + ((size_t)(b*16) * 2048 + q0) * 64, 64, Qb[0], t);
  __syncthreads();

  for (int h = 0; h < 16; h++){
    int par = h & 1;
    if (h + 1 < 16){
      size_t bh1 = (size_t)(b*16 + h + 1);
      stage_swz(Kh + (bh1 * 2048 + k0) * 64, 64, Kb[par ^ 1], t);
      stage_swz(Qh + (bh1 * 2048 + q0) * 64, 64, Qb[par ^ 1], t);
    }
    size_t bh = (size_t)(b*16 + h);
    f32x4 mh = *(const f32x4*)&Mo[bh * 2048 + qc0];
    f32x4 li = *(const f32x4*)&Lo[bh * 2048 + qc0];
    const char* qbase = (const char*)Qb[par] + qrow * 128;
    bf16x8 qb0 = *(const bf16x8*)(qbase + ((g*16)      ^ qsw));
    bf16x8 qb1 = *(const bf16x8*)(qbase + ((g*16 + 64) ^ qsw));
    #pragma unroll
    for (int kf = 0; kf < 4; kf++){
      const char* kbase = (const char*)Kb[par] + (kf*16 + ln15) * 128;
      bf16x8 ka0 = *(const bf16x8*)(kbase + ((g*16)      ^ qsw));
      bf16x8 ka1 = *(const bf16x8*)(kbase + ((g*16 + 64) ^ qsw));
      f32x4 z = {};
      z = mfma_bf16(ka0, qb0, z);
      z = mfma_bf16(ka1, qb1, z);
      #pragma unroll
      for (int r = 0; r < 4; r++){
        float a = exp2fast(z[r] * SC - mh[r]) * li[r];
        if (diag && (k0 + kf * 16 + ln15 > qc0 + r)) a = 0.f;
        am[kf][r] += a;
      }
    }
    __syncthreads();                       // drains vmcnt(0): stage(h+1) done
  }
  #pragma unroll
  for (int kf = 0; kf < 4; kf++)
    #pragma unroll
    for (int r = 0; r < 4; r++)
      outA[(size_t)(b*2048 + qc0 + r) * 2048 + k0 + kf * 16 + ln15] = am[kf][r] * 0.0625f;
}

// ---------------------------------------------------------------------------
extern "C" void kernel_launch(void* const* d_in, const int* in_sizes, int n_in,
                              void* d_out, int out_size, void* d_ws, size_t ws_size,
                              hipStream_t stream){
  const float* x   = (const float*)d_in[0];
  const float* Wq  = (const float*)d_in[1];
  const float* bq  = (const float*)d_in[2];
  const float* Wk  = (const float*)d_in[3];
  const float* bk  = (const float*)d_in[4];
  const float* Wv  = (const float*)d_in[5];
  const float* bv  = (const float*)d_in[6];
  const float* Wo  = (const float*)d_in[7];
  const float* bo  = (const float*)d_in[8];
  const float* g1  = (const float*)d_in[9];
  const float* b1  = (const float*)d_in[10];
  const float* g2  = (const float*)d_in[11];
  const float* b2  = (const float*)d_in[12];
  const float* Wm1 = (const float*)d_in[13];
  const float* bm1 = (const float*)d_in[14];
  const float* Wm2 = (const float*)d_in[15];
  const float* bm2 = (const float*)d_in[16];

  char* ws = (char*)d_ws;
  const size_t MB = (size_t)1 << 20;
  unsigned short* wqkv = (unsigned short*)(ws + 0*MB);    // 6 MB
  unsigned short* wto  = (unsigned short*)(ws + 6*MB);    // 2 MB
  unsigned short* wtm1 = (unsigned short*)(ws + 8*MB);    // 2 MB
  unsigned short* wtm2 = (unsigned short*)(ws + 10*MB);   // 2 MB
  float* bqkv = (float*)(ws + 12*MB);                     // 12 KB
  float* mbuf = (float*)(ws + 12*MB + 256*1024);          // 256 KB
  float* lbuf = (float*)(ws + 12*MB + 512*1024);          // 256 KB
  unsigned short* o    = (unsigned short*)(ws + 13*MB);   // 8 MB (later: ctx)
  unsigned short* qh   = (unsigned short*)(ws + 21*MB);   // 8 MB (later: h1)
  unsigned short* kh   = (unsigned short*)(ws + 29*MB);   // 8 MB
  unsigned short* vt   = (unsigned short*)(ws + 37*MB);   // 8 MB (later: hin)
  float* x2            = (float*)(ws + 45*MB);            // 16 MB
  unsigned short* ctx  = o;     // o dead after gemm_qkv
  unsigned short* hin  = vt;    // vt dead after flash
  unsigned short* h1   = qh;    // qh dead after amean

  float* outX = (float*)d_out;
  float* outA = outX + (size_t)2*2048*1024;

  transpose_all<<<dim3(32,32,6), dim3(32,8), 0, stream>>>(
      Wq, Wk, Wv, Wo, Wm1, Wm2,
      wqkv, wqkv + 1024*1024, wqkv + 2*1024*1024, wto, wtm1, wtm2);
  concat_bias<<<12, 256, 0, stream>>>(bq, bk, bv, bqkv);

  ln_kernel<<<4096, 256, 0, stream>>>(x, g1, b1, o);
  gemm_qkv<<<dim3(24,32), 256, 0, stream>>>(o, wqkv, bqkv, qh, kh, vt);

  flash_kernel<<<dim3(32,32), 256, 0, stream>>>(qh, kh, vt, ctx, mbuf, lbuf);
  amean_kernel<<<dim3(32,32,2), 256, 0, stream>>>(qh, kh, mbuf, lbuf, outA);

  gemm_bt<2><<<dim3(8,32), 256, 0, stream>>>(ctx, wto, bo, x, (void*)x2);
  ln_kernel<<<4096, 256, 0, stream>>>(x2, g2, b2, hin);
  gemm_bt<1><<<dim3(8,32), 256, 0, stream>>>(hin, wtm1, bm1, nullptr, h1);
  gemm_bt<2><<<dim3(8,32), 256, 0, stream>>>(h1, wtm2, bm2, x2, (void*)outX);
}